// Round 5
// baseline (977.102 us; speedup 1.0000x reference)
//
#include <hip/hip_runtime.h>
#include <hip/hip_bf16.h>

#define N_NODES 20000
#define N_EDGES 640000
#define HID 256
#define D_OP 140
#define D_EMB 64
#define D_CFG 52
#define LDX 512   // [x | agg] concatenated row (bf16 staging buffer)

typedef short bf16x8 __attribute__((ext_vector_type(8)));
typedef float f32x4 __attribute__((ext_vector_type(4)));

typedef __hip_bfloat16 bf16;

// ---------------- embed + concat + (x-mean)/std -> X2[:, 0:256] (fp32 in, bf16 out) ----------------
__global__ __launch_bounds__(256) void embed_kernel(
    const float* __restrict__ op_feats, const float* __restrict__ cfg,
    const float* __restrict__ emb, const float* __restrict__ mean,
    const float* __restrict__ stdv, const int* __restrict__ op_ids,
    bf16* __restrict__ X2)
{
    int n = blockIdx.x;
    int j = threadIdx.x;
    float v;
    if (j < D_OP)              v = op_feats[(size_t)n * D_OP + j];
    else if (j < D_OP + D_EMB) v = emb[(size_t)op_ids[n] * D_EMB + (j - D_OP)];
    else                       v = cfg[(size_t)n * D_CFG + (j - D_OP - D_EMB)];
    X2[(size_t)n * LDX + j] = __float2bfloat16((v - mean[j]) / stdv[j]);
}

// ---------------- build transposed bf16 weights from fp32 ----------------
// WTc[l][n][k] = (k<256 ? Wself[l][k][n] : Wneigh[l][k-256][n])   (4 x 256 x 512)
// W1T[n][k] = W1[k][n]  (256 x 256) ; W2T[n][k] = W2[k][n]  (128 x 256)
__global__ __launch_bounds__(256) void build_wt(
    const float* __restrict__ Wself, const float* __restrict__ Wneigh,
    const float* __restrict__ W1, const float* __restrict__ W2,
    bf16* __restrict__ WTc, bf16* __restrict__ W1T, bf16* __restrict__ W2T)
{
    int idx = blockIdx.x * 256 + threadIdx.x;
    const int NC = 4 * 256 * 512;
    if (idx < NC) {
        int l = idx >> 17;
        int rem = idx & 131071;
        int n = rem >> 9;
        int k = rem & 511;
        float v = (k < 256) ? Wself[l * 65536 + k * 256 + n]
                            : Wneigh[l * 65536 + (k - 256) * 256 + n];
        WTc[idx] = __float2bfloat16(v);
    } else if (idx < NC + 65536) {
        int i = idx - NC;
        int n = i >> 8, k = i & 255;
        W1T[i] = __float2bfloat16(W1[k * 256 + n]);
    } else if (idx < NC + 65536 + 32768) {
        int i = idx - NC - 65536;
        int n = i >> 8, k = i & 255;   // n < 128
        W2T[i] = __float2bfloat16(W2[k * 128 + n]);
    }
}

// ---------------- degree count ----------------
__global__ __launch_bounds__(256) void deg_kernel(const int* __restrict__ dst, int* __restrict__ deg)
{
    int e = blockIdx.x * 256 + threadIdx.x;
    if (e < N_EDGES) atomicAdd(&deg[dst[e]], 1);
}

// ---------------- exclusive scan of degrees (single block) ----------------
__global__ __launch_bounds__(1024) void scan_kernel(const int* __restrict__ deg, int* __restrict__ row_off)
{
    __shared__ int sdata[1024];
    int t = threadIdx.x;
    int base = t * 20;
    int local[20];
    int s = 0;
#pragma unroll
    for (int i = 0; i < 20; i++) {
        int idx = base + i;
        local[i] = (idx < N_NODES) ? deg[idx] : 0;
        s += local[i];
    }
    sdata[t] = s;
    __syncthreads();
    for (int off = 1; off < 1024; off <<= 1) {
        int v = (t >= off) ? sdata[t - off] : 0;
        __syncthreads();
        sdata[t] += v;
        __syncthreads();
    }
    int run = sdata[t] - s;  // exclusive
#pragma unroll
    for (int i = 0; i < 20; i++) {
        int idx = base + i;
        if (idx < N_NODES) { row_off[idx] = run; run += local[i]; }
    }
    if (t == 1023) row_off[N_NODES] = sdata[1023];
}

// ---------------- cursor init + inv_deg ----------------
__global__ __launch_bounds__(256) void prep_kernel(const int* __restrict__ deg,
    const int* __restrict__ row_off, int* __restrict__ cursor, float* __restrict__ inv_deg)
{
    int n = blockIdx.x * 256 + threadIdx.x;
    if (n < N_NODES) {
        cursor[n] = row_off[n];
        inv_deg[n] = 1.0f / fmaxf((float)deg[n], 1.0f);
    }
}

// ---------------- CSR fill: sorted src per dst ----------------
__global__ __launch_bounds__(256) void fill_kernel(const int* __restrict__ src,
    const int* __restrict__ dst, int* __restrict__ cursor, int* __restrict__ ssrc)
{
    int e = blockIdx.x * 256 + threadIdx.x;
    if (e < N_EDGES) {
        int d = dst[e];
        int pos = atomicAdd(&cursor[d], 1);
        ssrc[pos] = src[e];
    }
}

// ---------------- mean aggregation: X2[n, 256:512] = mean over in-edges of X2[src, 0:256] ----------------
__global__ __launch_bounds__(256) void agg_kernel(const bf16* X2,
    const int* __restrict__ row_off, const int* __restrict__ ssrc,
    const float* __restrict__ inv_deg, bf16* X2w)
{
    int n = blockIdx.x;
    int f = threadIdx.x;
    int e0 = row_off[n], e1 = row_off[n + 1];
    float acc = 0.0f;
    for (int e = e0; e < e1; ++e) {
        int s = ssrc[e];
        acc += __bfloat162float(X2[(size_t)s * LDX + f]);
    }
    X2w[(size_t)n * LDX + f] = __float2bfloat16(acc * inv_deg[n]);
}

// ---------------- fused GEMM + bias + LayerNorm + ReLU ----------------
// C[M x (NT*16)] = A[M x KDIM] @ WT^T (WT row-major [NT*16][KDIM] = B^T),
// then per-row LN (gamma,beta fp32) + relu; store OutT with row stride ldo.
// block = 256 threads = 4 waves; wave w owns rows [blk*64 + w*16, +16), all NT*16 cols.
// In-place safe: all A-loads drain (acc dependency) before any store; row ranges disjoint.
template <int NT, int KDIM, typename OutT>
__global__ __launch_bounds__(256) void gemm_ln_relu(
    const bf16* __restrict__ A, int lda,
    const bf16* __restrict__ WT,
    const float* __restrict__ bias,   // may be null
    const float* __restrict__ gamma, const float* __restrict__ beta,
    OutT* __restrict__ out, int ldo, int M)
{
    const int wid = threadIdx.x >> 6;
    const int lane = threadIdx.x & 63;
    const int r0 = blockIdx.x * 64 + wid * 16;
    if (r0 >= M) return;
    const int lr = lane & 15;   // A-row (input) / out-col (epilogue) within 16-tile
    const int kg = lane >> 4;   // 0..3

    f32x4 acc[NT];
#pragma unroll
    for (int i = 0; i < NT; i++) acc[i] = (f32x4){0.f, 0.f, 0.f, 0.f};

    const bf16* arow = A + (size_t)(r0 + lr) * lda + kg * 8;
#pragma unroll
    for (int k0 = 0; k0 < KDIM; k0 += 32) {
        bf16x8 a = *reinterpret_cast<const bf16x8*>(arow + k0);
#pragma unroll
        for (int nt = 0; nt < NT; nt++) {
            const bf16* bp = WT + (size_t)(nt * 16 + lr) * KDIM + k0 + kg * 8;
            bf16x8 b = *reinterpret_cast<const bf16x8*>(bp);
            acc[nt] = __builtin_amdgcn_mfma_f32_16x16x32_bf16(a, b, acc[nt], 0, 0, 0);
        }
    }

    // bias + LN stats. acc[nt][r] holds C[row = kg*4+r][col = nt*16+lr].
    const float Nf = (float)(NT * 16);
    float sum[4] = {0, 0, 0, 0}, sq[4] = {0, 0, 0, 0};
#pragma unroll
    for (int nt = 0; nt < NT; nt++) {
        int col = nt * 16 + lr;
        float bv = bias ? bias[col] : 0.0f;
#pragma unroll
        for (int r = 0; r < 4; r++) {
            float v = acc[nt][r] + bv;
            acc[nt][r] = v;
            sum[r] += v;
            sq[r] += v * v;
        }
    }
#pragma unroll
    for (int m = 1; m < 16; m <<= 1) {
#pragma unroll
        for (int r = 0; r < 4; r++) {
            sum[r] += __shfl_xor(sum[r], m, 64);
            sq[r]  += __shfl_xor(sq[r], m, 64);
        }
    }
    float mean_[4], rstd[4];
#pragma unroll
    for (int r = 0; r < 4; r++) {
        float mu = sum[r] / Nf;
        float var = sq[r] / Nf - mu * mu;
        mean_[r] = mu;
        rstd[r] = rsqrtf(var + 1e-5f);
    }
#pragma unroll
    for (int nt = 0; nt < NT; nt++) {
        int col = nt * 16 + lr;
        float g = gamma[col];
        float be = beta[col];
#pragma unroll
        for (int r = 0; r < 4; r++) {
            int row = r0 + kg * 4 + r;
            float v = (acc[nt][r] - mean_[r]) * rstd[r] * g + be;
            v = fmaxf(v, 0.0f);
            if constexpr (__is_same(OutT, float)) {
                out[(size_t)row * ldo + col] = v;
            } else {
                out[(size_t)row * ldo + col] = __float2bfloat16(v);
            }
        }
    }
}

extern "C" void kernel_launch(void* const* d_in, const int* in_sizes, int n_in,
                              void* d_out, int out_size, void* d_ws, size_t ws_size,
                              hipStream_t stream)
{
    const float* op_feats     = (const float*)d_in[0];
    const float* config_feats = (const float*)d_in[1];
    const float* embed_table  = (const float*)d_in[2];
    const float* feat_mean    = (const float*)d_in[3];
    const float* feat_std     = (const float*)d_in[4];
    const float* Wself        = (const float*)d_in[5];
    const float* Wneigh       = (const float*)d_in[6];
    const float* bconv        = (const float*)d_in[7];
    const float* conv_gamma   = (const float*)d_in[8];
    const float* conv_beta    = (const float*)d_in[9];
    const float* W1           = (const float*)d_in[10];
    const float* g1           = (const float*)d_in[11];
    const float* b1           = (const float*)d_in[12];
    const float* W2           = (const float*)d_in[13];
    const float* g2           = (const float*)d_in[14];
    const float* b2           = (const float*)d_in[15];
    const int* op_ids = (const int*)d_in[16];
    const int* src    = (const int*)d_in[17];
    const int* dst    = (const int*)d_in[18];

    char* w = (char*)d_ws;
    auto alloc = [&](size_t bytes) -> void* {
        void* p = (void*)w;
        w += (bytes + 255) & ~(size_t)255;
        return p;
    };
    bf16* X2  = (bf16*)alloc((size_t)N_NODES * LDX * 2);   // 20.5 MB, [x | agg] / [., h1]
    bf16* WTc = (bf16*)alloc((size_t)4 * 256 * 512 * 2);   // 4 MB
    bf16* W1T = (bf16*)alloc((size_t)256 * 256 * 2);
    bf16* W2T = (bf16*)alloc((size_t)128 * 256 * 2);
    int* deg     = (int*)alloc((size_t)N_NODES * 4);
    int* row_off = (int*)alloc((size_t)(N_NODES + 1) * 4);
    int* cursor  = (int*)alloc((size_t)N_NODES * 4);
    float* inv_deg = (float*)alloc((size_t)N_NODES * 4);
    int* ssrc    = (int*)alloc((size_t)N_EDGES * 4);       // 2.56 MB

    float* out = (float*)d_out;

    hipMemsetAsync(deg, 0, (size_t)N_NODES * 4, stream);

    build_wt<<<2432, 256, 0, stream>>>(Wself, Wneigh, W1, W2, WTc, W1T, W2T);
    embed_kernel<<<N_NODES, 256, 0, stream>>>(op_feats, config_feats, embed_table,
                                              feat_mean, feat_std, op_ids, X2);
    deg_kernel<<<(N_EDGES + 255) / 256, 256, 0, stream>>>(dst, deg);
    scan_kernel<<<1, 1024, 0, stream>>>(deg, row_off);
    prep_kernel<<<(N_NODES + 255) / 256, 256, 0, stream>>>(deg, row_off, cursor, inv_deg);
    fill_kernel<<<(N_EDGES + 255) / 256, 256, 0, stream>>>(src, dst, cursor, ssrc);

    const int GEMM_GRID = (N_NODES + 63) / 64;  // 313

    for (int l = 0; l < 4; ++l) {
        agg_kernel<<<N_NODES, 256, 0, stream>>>(X2, row_off, ssrc, inv_deg, X2 + 256);
        // in-place: reads X2[:, 0:512], writes X2[:, 0:256]
        gemm_ln_relu<16, 512, bf16><<<GEMM_GRID, 256, 0, stream>>>(
            X2, LDX, WTc + (size_t)l * 256 * 512,
            bconv + (size_t)l * 256, conv_gamma + (size_t)l * 256, conv_beta + (size_t)l * 256,
            X2, LDX, N_NODES);
    }
    // head: h1 -> X2[:, 256:512], then final fp32 -> d_out
    gemm_ln_relu<16, 256, bf16><<<GEMM_GRID, 256, 0, stream>>>(
        X2, LDX, W1T, (const float*)nullptr, g1, b1, X2 + 256, LDX, N_NODES);
    gemm_ln_relu<8, 256, float><<<GEMM_GRID, 256, 0, stream>>>(
        X2 + 256, LDX, W2T, (const float*)nullptr, g2, b2, out, 128, N_NODES);
    (void)ws_size; (void)n_in; (void)in_sizes; (void)out_size;
}

// Round 7
// 589.976 us; speedup vs baseline: 1.6562x; 1.6562x over previous
//
#include <hip/hip_runtime.h>
#include <hip/hip_bf16.h>
#include <string.h>

#define N_NODES 20000
#define N_EDGES 640000
#define HID 256
#define D_OP 140
#define D_EMB 64
#define D_CFG 52
#define LDX 512   // [x | agg] concatenated row (bf16 staging buffer)

typedef short bf16x8 __attribute__((ext_vector_type(8)));
typedef short bf16x4 __attribute__((ext_vector_type(4)));
typedef float f32x4 __attribute__((ext_vector_type(4)));

typedef __hip_bfloat16 bf16;

__device__ inline float b2f(short s) {
    unsigned int u = ((unsigned int)(unsigned short)s) << 16;
    float f; __builtin_memcpy(&f, &u, 4); return f;
}
__device__ inline short f2b(float f) {
    __hip_bfloat16 h = __float2bfloat16(f);
    short s; __builtin_memcpy(&s, &h, 2); return s;
}

// ---------------- embed + concat + (x-mean)/std -> X2[:, 0:256] (fp32 in, bf16 out) ----------------
__global__ __launch_bounds__(256) void embed_kernel(
    const float* __restrict__ op_feats, const float* __restrict__ cfg,
    const float* __restrict__ emb, const float* __restrict__ mean,
    const float* __restrict__ stdv, const int* __restrict__ op_ids,
    bf16* __restrict__ X2)
{
    int n = blockIdx.x;
    int j = threadIdx.x;
    float v;
    if (j < D_OP)              v = op_feats[(size_t)n * D_OP + j];
    else if (j < D_OP + D_EMB) v = emb[(size_t)op_ids[n] * D_EMB + (j - D_OP)];
    else                       v = cfg[(size_t)n * D_CFG + (j - D_OP - D_EMB)];
    X2[(size_t)n * LDX + j] = __float2bfloat16((v - mean[j]) / stdv[j]);
}

// ---------------- build transposed bf16 weights from fp32 ----------------
// WTc[l][n][k] = (k<256 ? Wself[l][k][n] : Wneigh[l][k-256][n])   (4 x 256 x 512)
// W1T[n][k] = W1[k][n]  (256 x 256) ; W2T[n][k] = W2[k][n]  (128 x 256)
__global__ __launch_bounds__(256) void build_wt(
    const float* __restrict__ Wself, const float* __restrict__ Wneigh,
    const float* __restrict__ W1, const float* __restrict__ W2,
    bf16* __restrict__ WTc, bf16* __restrict__ W1T, bf16* __restrict__ W2T)
{
    int idx = blockIdx.x * 256 + threadIdx.x;
    const int NC = 4 * 256 * 512;
    if (idx < NC) {
        int l = idx >> 17;
        int rem = idx & 131071;
        int n = rem >> 9;
        int k = rem & 511;
        float v = (k < 256) ? Wself[l * 65536 + k * 256 + n]
                            : Wneigh[l * 65536 + (k - 256) * 256 + n];
        WTc[idx] = __float2bfloat16(v);
    } else if (idx < NC + 65536) {
        int i = idx - NC;
        int n = i >> 8, k = i & 255;
        W1T[i] = __float2bfloat16(W1[k * 256 + n]);
    } else if (idx < NC + 65536 + 32768) {
        int i = idx - NC - 65536;
        int n = i >> 8, k = i & 255;   // n < 128
        W2T[i] = __float2bfloat16(W2[k * 128 + n]);
    }
}

// ---------------- degree count ----------------
__global__ __launch_bounds__(256) void deg_kernel(const int* __restrict__ dst, int* __restrict__ deg)
{
    int e = blockIdx.x * 256 + threadIdx.x;
    if (e < N_EDGES) atomicAdd(&deg[dst[e]], 1);
}

// ---------------- exclusive scan of degrees (single block) ----------------
__global__ __launch_bounds__(1024) void scan_kernel(const int* __restrict__ deg, int* __restrict__ row_off)
{
    __shared__ int sdata[1024];
    int t = threadIdx.x;
    int base = t * 20;
    int local[20];
    int s = 0;
#pragma unroll
    for (int i = 0; i < 20; i++) {
        int idx = base + i;
        local[i] = (idx < N_NODES) ? deg[idx] : 0;
        s += local[i];
    }
    sdata[t] = s;
    __syncthreads();
    for (int off = 1; off < 1024; off <<= 1) {
        int v = (t >= off) ? sdata[t - off] : 0;
        __syncthreads();
        sdata[t] += v;
        __syncthreads();
    }
    int run = sdata[t] - s;  // exclusive
#pragma unroll
    for (int i = 0; i < 20; i++) {
        int idx = base + i;
        if (idx < N_NODES) { row_off[idx] = run; run += local[i]; }
    }
    if (t == 1023) row_off[N_NODES] = sdata[1023];
}

// ---------------- cursor init + inv_deg ----------------
__global__ __launch_bounds__(256) void prep_kernel(const int* __restrict__ deg,
    const int* __restrict__ row_off, int* __restrict__ cursor, float* __restrict__ inv_deg)
{
    int n = blockIdx.x * 256 + threadIdx.x;
    if (n < N_NODES) {
        cursor[n] = row_off[n];
        inv_deg[n] = 1.0f / fmaxf((float)deg[n], 1.0f);
    }
}

// ---------------- CSR fill: sorted src per dst ----------------
__global__ __launch_bounds__(256) void fill_kernel(const int* __restrict__ src,
    const int* __restrict__ dst, int* __restrict__ cursor, int* __restrict__ ssrc)
{
    int e = blockIdx.x * 256 + threadIdx.x;
    if (e < N_EDGES) {
        int d = dst[e];
        int pos = atomicAdd(&cursor[d], 1);
        ssrc[pos] = src[e];
    }
}

// ---------------- mean aggregation: X2[n, 256:512] = mean over in-edges of X2[src, 0:256] ----------------
// one WAVE per node; lane l owns features [4l, 4l+4) -> one 8B load covers a whole 512B row per wave.
__global__ __launch_bounds__(256) void agg_kernel(const bf16* __restrict__ X2,
    const int* __restrict__ row_off, const int* __restrict__ ssrc,
    const float* __restrict__ inv_deg, bf16* __restrict__ X2w)
{
    const int wid = threadIdx.x >> 6;
    const int lane = threadIdx.x & 63;
    const int n = blockIdx.x * 4 + wid;
    if (n >= N_NODES) return;   // no barriers in this kernel: wave-level return OK
    const int e0 = row_off[n], e1 = row_off[n + 1];
    const size_t fo = (size_t)lane * 4;
    float a0 = 0.f, a1 = 0.f, a2 = 0.f, a3 = 0.f;
    int e = e0;
    for (; e + 1 < e1; e += 2) {
        int s0 = ssrc[e], s1 = ssrc[e + 1];
        bf16x4 v0 = *reinterpret_cast<const bf16x4*>(X2 + (size_t)s0 * LDX + fo);
        bf16x4 v1 = *reinterpret_cast<const bf16x4*>(X2 + (size_t)s1 * LDX + fo);
        a0 += b2f(v0.x) + b2f(v1.x);
        a1 += b2f(v0.y) + b2f(v1.y);
        a2 += b2f(v0.z) + b2f(v1.z);
        a3 += b2f(v0.w) + b2f(v1.w);
    }
    if (e < e1) {
        int s0 = ssrc[e];
        bf16x4 v0 = *reinterpret_cast<const bf16x4*>(X2 + (size_t)s0 * LDX + fo);
        a0 += b2f(v0.x); a1 += b2f(v0.y); a2 += b2f(v0.z); a3 += b2f(v0.w);
    }
    const float id = inv_deg[n];
    bf16x4 o;
    o.x = f2b(a0 * id); o.y = f2b(a1 * id); o.z = f2b(a2 * id); o.w = f2b(a3 * id);
    *reinterpret_cast<bf16x4*>(X2w + (size_t)n * LDX + fo) = o;
}

// ---------------- fused GEMM + bias + LayerNorm + ReLU (LDS-staged B) ----------------
// C[M x (NT*16)] = A[M x KDIM] @ WT^T (WT row-major [NT*16][KDIM] = B^T),
// per-row LN (gamma,beta fp32) + relu; store OutT with row stride ldo.
// block = 256 threads = 4 waves; wave w owns rows [blk*64 + w*16, +16).
// B is staged per-block into LDS in BK=64 chunks, double-buffered, padded rows
// (72 bf16 = 144B stride) for bank-phase-uniform ds_read_b128 / ds_write_b128.
// In-place safe: each block reads only its own 64 A-rows and writes those rows.
template <int NT, int KDIM, typename OutT>
__global__ __launch_bounds__(256) void gemm_ln_relu(
    const bf16* __restrict__ A, int lda,
    const bf16* __restrict__ WT,
    const float* __restrict__ bias,   // may be null
    const float* __restrict__ gamma, const float* __restrict__ beta,
    OutT* __restrict__ out, int ldo, int M)
{
    constexpr int NCOLS = NT * 16;
    constexpr int BK = 64;
    constexpr int NCHUNK = KDIM / BK;
    __shared__ __align__(16) short Bs[2][NCOLS][72];

    const int wid = threadIdx.x >> 6;
    const int lane = threadIdx.x & 63;
    const int r0 = blockIdx.x * 64 + wid * 16;
    const int lr = lane & 15;   // A-row (input) / out-col (epilogue) within 16-tile
    const int kg = lane >> 4;   // 0..3

    f32x4 acc[NT];
#pragma unroll
    for (int i = 0; i < NT; i++) acc[i] = (f32x4){0.f, 0.f, 0.f, 0.f};

    // clamp so every wave participates in barriers even past M
    const int arow_idx = (r0 + lr < M) ? (r0 + lr) : (M - 1);
    const bf16* arow = A + (size_t)arow_idx * lda + kg * 8;

    auto stage = [&](int buf, int kbase) {
#pragma unroll
        for (int c = threadIdx.x; c < NCOLS * 8; c += 256) {
            int n = c >> 3, slot = c & 7;
            bf16x8 v = *reinterpret_cast<const bf16x8*>(WT + (size_t)n * KDIM + kbase + slot * 8);
            *reinterpret_cast<bf16x8*>(&Bs[buf][n][slot * 8]) = v;
        }
    };

    bf16x8 aCur0 = *reinterpret_cast<const bf16x8*>(arow);
    bf16x8 aCur1 = *reinterpret_cast<const bf16x8*>(arow + 32);
    stage(0, 0);
    __syncthreads();

    for (int c = 0; c < NCHUNK; ++c) {
        bf16x8 aN0, aN1;
        if (c + 1 < NCHUNK) {
            stage((c + 1) & 1, (c + 1) * BK);
            aN0 = *reinterpret_cast<const bf16x8*>(arow + (c + 1) * BK);
            aN1 = *reinterpret_cast<const bf16x8*>(arow + (c + 1) * BK + 32);
        }
        const int buf = c & 1;
#pragma unroll
        for (int nt = 0; nt < NT; ++nt) {
            const short* bp = &Bs[buf][nt * 16 + lr][kg * 8];
            bf16x8 b0 = *reinterpret_cast<const bf16x8*>(bp);
            bf16x8 b1 = *reinterpret_cast<const bf16x8*>(bp + 32);
            acc[nt] = __builtin_amdgcn_mfma_f32_16x16x32_bf16(aCur0, b0, acc[nt], 0, 0, 0);
            acc[nt] = __builtin_amdgcn_mfma_f32_16x16x32_bf16(aCur1, b1, acc[nt], 0, 0, 0);
        }
        if (c + 1 < NCHUNK) { aCur0 = aN0; aCur1 = aN1; }
        __syncthreads();
    }

    // bias + LN stats. acc[nt][r] holds C[row = kg*4+r][col = nt*16+lr].
    const float Nf = (float)NCOLS;
    float sum[4] = {0, 0, 0, 0}, sq[4] = {0, 0, 0, 0};
#pragma unroll
    for (int nt = 0; nt < NT; nt++) {
        int col = nt * 16 + lr;
        float bv = bias ? bias[col] : 0.0f;
#pragma unroll
        for (int r = 0; r < 4; r++) {
            float v = acc[nt][r] + bv;
            acc[nt][r] = v;
            sum[r] += v;
            sq[r] += v * v;
        }
    }
#pragma unroll
    for (int m = 1; m < 16; m <<= 1) {
#pragma unroll
        for (int r = 0; r < 4; r++) {
            sum[r] += __shfl_xor(sum[r], m, 64);
            sq[r]  += __shfl_xor(sq[r], m, 64);
        }
    }
    float mean_[4], rstd[4];
#pragma unroll
    for (int r = 0; r < 4; r++) {
        float mu = sum[r] / Nf;
        float var = sq[r] / Nf - mu * mu;
        mean_[r] = mu;
        rstd[r] = rsqrtf(var + 1e-5f);
    }
#pragma unroll
    for (int nt = 0; nt < NT; nt++) {
        int col = nt * 16 + lr;
        float g = gamma[col];
        float be = beta[col];
#pragma unroll
        for (int r = 0; r < 4; r++) {
            int row = r0 + kg * 4 + r;
            if (row < M) {
                float v = (acc[nt][r] - mean_[r]) * rstd[r] * g + be;
                v = fmaxf(v, 0.0f);
                if constexpr (__is_same(OutT, float)) {
                    out[(size_t)row * ldo + col] = v;
                } else {
                    out[(size_t)row * ldo + col] = __float2bfloat16(v);
                }
            }
        }
    }
}

extern "C" void kernel_launch(void* const* d_in, const int* in_sizes, int n_in,
                              void* d_out, int out_size, void* d_ws, size_t ws_size,
                              hipStream_t stream)
{
    const float* op_feats     = (const float*)d_in[0];
    const float* config_feats = (const float*)d_in[1];
    const float* embed_table  = (const float*)d_in[2];
    const float* feat_mean    = (const float*)d_in[3];
    const float* feat_std     = (const float*)d_in[4];
    const float* Wself        = (const float*)d_in[5];
    const float* Wneigh       = (const float*)d_in[6];
    const float* bconv        = (const float*)d_in[7];
    const float* conv_gamma   = (const float*)d_in[8];
    const float* conv_beta    = (const float*)d_in[9];
    const float* W1           = (const float*)d_in[10];
    const float* g1           = (const float*)d_in[11];
    const float* b1           = (const float*)d_in[12];
    const float* W2           = (const float*)d_in[13];
    const float* g2           = (const float*)d_in[14];
    const float* b2           = (const float*)d_in[15];
    const int* op_ids = (const int*)d_in[16];
    const int* src    = (const int*)d_in[17];
    const int* dst    = (const int*)d_in[18];

    char* w = (char*)d_ws;
    auto alloc = [&](size_t bytes) -> void* {
        void* p = (void*)w;
        w += (bytes + 255) & ~(size_t)255;
        return p;
    };
    bf16* X2  = (bf16*)alloc((size_t)N_NODES * LDX * 2);   // 20.5 MB, [x | agg] / [., h1]
    bf16* WTc = (bf16*)alloc((size_t)4 * 256 * 512 * 2);   // 4 MB
    bf16* W1T = (bf16*)alloc((size_t)256 * 256 * 2);
    bf16* W2T = (bf16*)alloc((size_t)128 * 256 * 2);
    int* deg     = (int*)alloc((size_t)N_NODES * 4);
    int* row_off = (int*)alloc((size_t)(N_NODES + 1) * 4);
    int* cursor  = (int*)alloc((size_t)N_NODES * 4);
    float* inv_deg = (float*)alloc((size_t)N_NODES * 4);
    int* ssrc    = (int*)alloc((size_t)N_EDGES * 4);       // 2.56 MB

    float* out = (float*)d_out;

    hipMemsetAsync(deg, 0, (size_t)N_NODES * 4, stream);

    build_wt<<<2432, 256, 0, stream>>>(Wself, Wneigh, W1, W2, WTc, W1T, W2T);
    embed_kernel<<<N_NODES, 256, 0, stream>>>(op_feats, config_feats, embed_table,
                                              feat_mean, feat_std, op_ids, X2);
    deg_kernel<<<(N_EDGES + 255) / 256, 256, 0, stream>>>(dst, deg);
    scan_kernel<<<1, 1024, 0, stream>>>(deg, row_off);
    prep_kernel<<<(N_NODES + 255) / 256, 256, 0, stream>>>(deg, row_off, cursor, inv_deg);
    fill_kernel<<<(N_EDGES + 255) / 256, 256, 0, stream>>>(src, dst, cursor, ssrc);

    const int GEMM_GRID = (N_NODES + 63) / 64;  // 313
    const int AGG_GRID  = (N_NODES + 3) / 4;    // 5000

    for (int l = 0; l < 4; ++l) {
        agg_kernel<<<AGG_GRID, 256, 0, stream>>>(X2, row_off, ssrc, inv_deg, X2 + 256);
        // in-place: reads X2[:, 0:512], writes X2[:, 0:256]
        gemm_ln_relu<16, 512, bf16><<<GEMM_GRID, 256, 0, stream>>>(
            X2, LDX, WTc + (size_t)l * 256 * 512,
            bconv + (size_t)l * 256, conv_gamma + (size_t)l * 256, conv_beta + (size_t)l * 256,
            X2, LDX, N_NODES);
    }
    // head: h1 -> X2[:, 256:512], then final fp32 -> d_out
    gemm_ln_relu<16, 256, bf16><<<GEMM_GRID, 256, 0, stream>>>(
        X2, LDX, W1T, (const float*)nullptr, g1, b1, X2 + 256, LDX, N_NODES);
    gemm_ln_relu<8, 256, float><<<GEMM_GRID, 256, 0, stream>>>(
        X2 + 256, LDX, W2T, (const float*)nullptr, g2, b2, out, 128, N_NODES);
    (void)ws_size; (void)n_in; (void)in_sizes; (void)out_size;
}

// Round 16
// 472.176 us; speedup vs baseline: 2.0694x; 1.2495x over previous
//
#include <hip/hip_runtime.h>
#include <hip/hip_bf16.h>
#include <string.h>

#define N_NODES 20000
#define N_EDGES 640000
#define HID 256
#define D_OP 140
#define D_EMB 64
#define D_CFG 52
#define LDX 512   // [x | agg] concatenated row (bf16 staging buffer)

typedef short bf16x8 __attribute__((ext_vector_type(8)));
typedef short bf16x4 __attribute__((ext_vector_type(4)));
typedef float f32x4 __attribute__((ext_vector_type(4)));

typedef __hip_bfloat16 bf16;

__device__ inline float b2f(short s) {
    unsigned int u = ((unsigned int)(unsigned short)s) << 16;
    float f; __builtin_memcpy(&f, &u, 4); return f;
}
__device__ inline short f2b(float f) {
    __hip_bfloat16 h = __float2bfloat16(f);
    short s; __builtin_memcpy(&s, &h, 2); return s;
}

// ---------------- embed + concat + (x-mean)/std -> X2[:, 0:256] (fp32 in, bf16 out) ----------------
__global__ __launch_bounds__(256) void embed_kernel(
    const float* __restrict__ op_feats, const float* __restrict__ cfg,
    const float* __restrict__ emb, const float* __restrict__ mean,
    const float* __restrict__ stdv, const int* __restrict__ op_ids,
    bf16* __restrict__ X2)
{
    int n = blockIdx.x;
    int j = threadIdx.x;
    float v;
    if (j < D_OP)              v = op_feats[(size_t)n * D_OP + j];
    else if (j < D_OP + D_EMB) v = emb[(size_t)op_ids[n] * D_EMB + (j - D_OP)];
    else                       v = cfg[(size_t)n * D_CFG + (j - D_OP - D_EMB)];
    X2[(size_t)n * LDX + j] = __float2bfloat16((v - mean[j]) / stdv[j]);
}

// ---------------- build transposed bf16 weights from fp32 ----------------
__global__ __launch_bounds__(256) void build_wt(
    const float* __restrict__ Wself, const float* __restrict__ Wneigh,
    const float* __restrict__ W1, const float* __restrict__ W2,
    bf16* __restrict__ WTc, bf16* __restrict__ W1T, bf16* __restrict__ W2T)
{
    int idx = blockIdx.x * 256 + threadIdx.x;
    const int NC = 4 * 256 * 512;
    if (idx < NC) {
        int l = idx >> 17;
        int rem = idx & 131071;
        int n = rem >> 9;
        int k = rem & 511;
        float v = (k < 256) ? Wself[l * 65536 + k * 256 + n]
                            : Wneigh[l * 65536 + (k - 256) * 256 + n];
        WTc[idx] = __float2bfloat16(v);
    } else if (idx < NC + 65536) {
        int i = idx - NC;
        int n = i >> 8, k = i & 255;
        W1T[i] = __float2bfloat16(W1[k * 256 + n]);
    } else if (idx < NC + 65536 + 32768) {
        int i = idx - NC - 65536;
        int n = i >> 8, k = i & 255;   // n < 128
        W2T[i] = __float2bfloat16(W2[k * 128 + n]);
    }
}

// ---------------- degree count ----------------
__global__ __launch_bounds__(256) void deg_kernel(const int* __restrict__ dst, int* __restrict__ deg)
{
    int e = blockIdx.x * 256 + threadIdx.x;
    if (e < N_EDGES) atomicAdd(&deg[dst[e]], 1);
}

// ---------------- exclusive scan of degrees (single block) ----------------
__global__ __launch_bounds__(1024) void scan_kernel(const int* __restrict__ deg, int* __restrict__ row_off)
{
    __shared__ int sdata[1024];
    int t = threadIdx.x;
    int base = t * 20;
    int local[20];
    int s = 0;
#pragma unroll
    for (int i = 0; i < 20; i++) {
        int idx = base + i;
        local[i] = (idx < N_NODES) ? deg[idx] : 0;
        s += local[i];
    }
    sdata[t] = s;
    __syncthreads();
    for (int off = 1; off < 1024; off <<= 1) {
        int v = (t >= off) ? sdata[t - off] : 0;
        __syncthreads();
        sdata[t] += v;
        __syncthreads();
    }
    int run = sdata[t] - s;  // exclusive
#pragma unroll
    for (int i = 0; i < 20; i++) {
        int idx = base + i;
        if (idx < N_NODES) { row_off[idx] = run; run += local[i]; }
    }
    if (t == 1023) row_off[N_NODES] = sdata[1023];
}

// ---------------- cursor init + inv_deg ----------------
__global__ __launch_bounds__(256) void prep_kernel(const int* __restrict__ deg,
    const int* __restrict__ row_off, int* __restrict__ cursor, float* __restrict__ inv_deg)
{
    int n = blockIdx.x * 256 + threadIdx.x;
    if (n < N_NODES) {
        cursor[n] = row_off[n];
        inv_deg[n] = 1.0f / fmaxf((float)deg[n], 1.0f);
    }
}

// ---------------- CSR fill: sorted src per dst ----------------
__global__ __launch_bounds__(256) void fill_kernel(const int* __restrict__ src,
    const int* __restrict__ dst, int* __restrict__ cursor, int* __restrict__ ssrc)
{
    int e = blockIdx.x * 256 + threadIdx.x;
    if (e < N_EDGES) {
        int d = dst[e];
        int pos = atomicAdd(&cursor[d], 1);
        ssrc[pos] = src[e];
    }
}

// ---------------- mean aggregation: X2[n, 256:512] = mean over in-edges of X2[src, 0:256] ----------------
// one WAVE per node, HALF-WAVE per edge: lanes 0-31 edge e, lanes 32-63 edge e+1;
// lane covers 8 features (16B load) -> 2 edges' full 512B rows per iteration, 2 pairs unrolled.
__global__ __launch_bounds__(256) void agg_kernel(const bf16* __restrict__ X2,
    const int* __restrict__ row_off, const int* __restrict__ ssrc,
    const float* __restrict__ inv_deg, bf16* __restrict__ X2w)
{
    const int wid = threadIdx.x >> 6;
    const int lane = threadIdx.x & 63;
    const int half = lane >> 5;    // which edge of the pair
    const int hl = lane & 31;      // feature slice: [8*hl, 8*hl+8)
    const int n = blockIdx.x * 4 + wid;
    if (n >= N_NODES) return;   // no barriers in this kernel: wave-level return OK
    const int e0 = row_off[n], e1 = row_off[n + 1];
    const size_t fo = (size_t)hl * 8;
    float a[8] = {0.f, 0.f, 0.f, 0.f, 0.f, 0.f, 0.f, 0.f};

    int e = e0 + half;             // this half-wave's edge list: e0+half, +2, +4, ...
    while (e + 2 < e1) {           // both e and e+2 valid
        int s0 = ssrc[e], s1 = ssrc[e + 2];
        bf16x8 v0 = *reinterpret_cast<const bf16x8*>(X2 + (size_t)s0 * LDX + fo);
        bf16x8 v1 = *reinterpret_cast<const bf16x8*>(X2 + (size_t)s1 * LDX + fo);
#pragma unroll
        for (int j = 0; j < 8; j++) a[j] += b2f(v0[j]) + b2f(v1[j]);
        e += 4;
    }
    if (e < e1) {
        int s0 = ssrc[e];
        bf16x8 v0 = *reinterpret_cast<const bf16x8*>(X2 + (size_t)s0 * LDX + fo);
#pragma unroll
        for (int j = 0; j < 8; j++) a[j] += b2f(v0[j]);
    }
    // combine the two half-wave edge partitions
#pragma unroll
    for (int j = 0; j < 8; j++) a[j] += __shfl_xor(a[j], 32, 64);

    if (half == 0) {
        const float id = inv_deg[n];
        bf16x8 o;
#pragma unroll
        for (int j = 0; j < 8; j++) o[j] = f2b(a[j] * id);
        *reinterpret_cast<bf16x8*>(X2w + (size_t)n * LDX + fo) = o;
    }
}

// ---------------- fused GEMM + bias + LayerNorm + ReLU (LDS-staged B, async-split stage) ----------------
// C[M x (NT*16)] = A[M x KDIM] @ WT^T (WT row-major [NT*16][KDIM] = B^T),
// per-row LN + relu; store OutT with row stride ldo.
// block = 256 threads = 4 waves; wave w owns rows [blk*64 + w*16, +16).
// Per chunk: issue global loads for chunk c+1 into REGISTERS -> MFMA chunk c (hides the
// load latency) -> ds_write chunk c+1 -> one barrier. Safety: buf[(c+1)&1] was last read
// in iter c-1, and every wave has passed barrier c-1 before any iter-c ds_write.
// In-place safe: each block reads only its own 64 A-rows and writes those rows.
template <int NT, int KDIM, typename OutT>
__global__ __launch_bounds__(256) void gemm_ln_relu(
    const bf16* __restrict__ A, int lda,
    const bf16* __restrict__ WT,
    const float* __restrict__ bias,   // may be null
    const float* __restrict__ gamma, const float* __restrict__ beta,
    OutT* __restrict__ out, int ldo, int M)
{
    constexpr int NCOLS = NT * 16;
    constexpr int BK = 64;
    constexpr int NCHUNK = KDIM / BK;
    constexpr int SREG = NT / 2;      // 16B loads per thread per chunk
    __shared__ __align__(16) short Bs[2][NCOLS][72];   // 72*2=144B row stride: 16B-aligned rows, 2-way-max read aliasing

    const int wid = threadIdx.x >> 6;
    const int lane = threadIdx.x & 63;
    const int r0 = blockIdx.x * 64 + wid * 16;
    const int lr = lane & 15;   // A-row (input) / out-col (epilogue) within 16-tile
    const int kg = lane >> 4;   // 0..3

    f32x4 acc[NT];
#pragma unroll
    for (int i = 0; i < NT; i++) acc[i] = (f32x4){0.f, 0.f, 0.f, 0.f};

    // clamp so every wave participates in barriers even past M
    const int arow_idx = (r0 + lr < M) ? (r0 + lr) : (M - 1);
    const bf16* arow = A + (size_t)arow_idx * lda + kg * 8;

    bf16x8 sreg[SREG];
    auto issue = [&](int kbase) {
#pragma unroll
        for (int i = 0; i < SREG; ++i) {
            int c = threadIdx.x + i * 256;
            int nrow = c >> 3, slot = c & 7;
            sreg[i] = *reinterpret_cast<const bf16x8*>(WT + (size_t)nrow * KDIM + kbase + slot * 8);
        }
    };
    auto commit = [&](int buf) {
#pragma unroll
        for (int i = 0; i < SREG; ++i) {
            int c = threadIdx.x + i * 256;
            int nrow = c >> 3, slot = c & 7;
            *reinterpret_cast<bf16x8*>(&Bs[buf][nrow][slot * 8]) = sreg[i];
        }
    };

    issue(0);
    bf16x8 aCur0 = *reinterpret_cast<const bf16x8*>(arow);
    bf16x8 aCur1 = *reinterpret_cast<const bf16x8*>(arow + 32);
    commit(0);
    __syncthreads();

    for (int c = 0; c < NCHUNK; ++c) {
        const int buf = c & 1;
        bf16x8 aN0, aN1;
        if (c + 1 < NCHUNK) {
            issue((c + 1) * BK);     // in flight during MFMA below
            aN0 = *reinterpret_cast<const bf16x8*>(arow + (c + 1) * BK);
            aN1 = *reinterpret_cast<const bf16x8*>(arow + (c + 1) * BK + 32);
        }
#pragma unroll
        for (int nt = 0; nt < NT; ++nt) {
            const short* bp = &Bs[buf][nt * 16 + lr][kg * 8];
            bf16x8 b0 = *reinterpret_cast<const bf16x8*>(bp);
            bf16x8 b1 = *reinterpret_cast<const bf16x8*>(bp + 32);
            acc[nt] = __builtin_amdgcn_mfma_f32_16x16x32_bf16(aCur0, b0, acc[nt], 0, 0, 0);
            acc[nt] = __builtin_amdgcn_mfma_f32_16x16x32_bf16(aCur1, b1, acc[nt], 0, 0, 0);
        }
        if (c + 1 < NCHUNK) {
            commit(buf ^ 1);         // vmcnt wait lands here, after the MFMAs
            aCur0 = aN0; aCur1 = aN1;
        }
        __syncthreads();
    }

    // bias + LN stats. acc[nt][r] holds C[row = kg*4+r][col = nt*16+lr].
    const float Nf = (float)NCOLS;
    float sum[4] = {0, 0, 0, 0}, sq[4] = {0, 0, 0, 0};
#pragma unroll
    for (int nt = 0; nt < NT; nt++) {
        int col = nt * 16 + lr;
        float bv = bias ? bias[col] : 0.0f;
#pragma unroll
        for (int r = 0; r < 4; r++) {
            float v = acc[nt][r] + bv;
            acc[nt][r] = v;
            sum[r] += v;
            sq[r] += v * v;
        }
    }
#pragma unroll
    for (int m = 1; m < 16; m <<= 1) {
#pragma unroll
        for (int r = 0; r < 4; r++) {
            sum[r] += __shfl_xor(sum[r], m, 64);
            sq[r]  += __shfl_xor(sq[r], m, 64);
        }
    }
    float mean_[4], rstd[4];
#pragma unroll
    for (int r = 0; r < 4; r++) {
        float mu = sum[r] / Nf;
        float var = sq[r] / Nf - mu * mu;
        mean_[r] = mu;
        rstd[r] = rsqrtf(var + 1e-5f);
    }
#pragma unroll
    for (int nt = 0; nt < NT; nt++) {
        int col = nt * 16 + lr;
        float g = gamma[col];
        float be = beta[col];
#pragma unroll
        for (int r = 0; r < 4; r++) {
            int row = r0 + kg * 4 + r;
            if (row < M) {
                float v = (acc[nt][r] - mean_[r]) * rstd[r] * g + be;
                v = fmaxf(v, 0.0f);
                if constexpr (__is_same(OutT, float)) {
                    out[(size_t)row * ldo + col] = v;
                } else {
                    out[(size_t)row * ldo + col] = __float2bfloat16(v);
                }
            }
        }
    }
}

extern "C" void kernel_launch(void* const* d_in, const int* in_sizes, int n_in,
                              void* d_out, int out_size, void* d_ws, size_t ws_size,
                              hipStream_t stream)
{
    const float* op_feats     = (const float*)d_in[0];
    const float* config_feats = (const float*)d_in[1];
    const float* embed_table  = (const float*)d_in[2];
    const float* feat_mean    = (const float*)d_in[3];
    const float* feat_std     = (const float*)d_in[4];
    const float* Wself        = (const float*)d_in[5];
    const float* Wneigh       = (const float*)d_in[6];
    const float* bconv        = (const float*)d_in[7];
    const float* conv_gamma   = (const float*)d_in[8];
    const float* conv_beta    = (const float*)d_in[9];
    const float* W1           = (const float*)d_in[10];
    const float* g1           = (const float*)d_in[11];
    const float* b1           = (const float*)d_in[12];
    const float* W2           = (const float*)d_in[13];
    const float* g2           = (const float*)d_in[14];
    const float* b2           = (const float*)d_in[15];
    const int* op_ids = (const int*)d_in[16];
    const int* src    = (const int*)d_in[17];
    const int* dst    = (const int*)d_in[18];

    char* w = (char*)d_ws;
    auto alloc = [&](size_t bytes) -> void* {
        void* p = (void*)w;
        w += (bytes + 255) & ~(size_t)255;
        return p;
    };
    bf16* X2  = (bf16*)alloc((size_t)N_NODES * LDX * 2);   // 20.5 MB, [x | agg] / [., h1]
    bf16* WTc = (bf16*)alloc((size_t)4 * 256 * 512 * 2);   // 4 MB
    bf16* W1T = (bf16*)alloc((size_t)256 * 256 * 2);
    bf16* W2T = (bf16*)alloc((size_t)128 * 256 * 2);
    int* deg     = (int*)alloc((size_t)N_NODES * 4);
    int* row_off = (int*)alloc((size_t)(N_NODES + 1) * 4);
    int* cursor  = (int*)alloc((size_t)N_NODES * 4);
    float* inv_deg = (float*)alloc((size_t)N_NODES * 4);
    int* ssrc    = (int*)alloc((size_t)N_EDGES * 4);       // 2.56 MB

    float* out = (float*)d_out;

    hipMemsetAsync(deg, 0, (size_t)N_NODES * 4, stream);

    build_wt<<<2432, 256, 0, stream>>>(Wself, Wneigh, W1, W2, WTc, W1T, W2T);
    embed_kernel<<<N_NODES, 256, 0, stream>>>(op_feats, config_feats, embed_table,
                                              feat_mean, feat_std, op_ids, X2);
    deg_kernel<<<(N_EDGES + 255) / 256, 256, 0, stream>>>(dst, deg);
    scan_kernel<<<1, 1024, 0, stream>>>(deg, row_off);
    prep_kernel<<<(N_NODES + 255) / 256, 256, 0, stream>>>(deg, row_off, cursor, inv_deg);
    fill_kernel<<<(N_EDGES + 255) / 256, 256, 0, stream>>>(src, dst, cursor, ssrc);

    const int GEMM_GRID = (N_NODES + 63) / 64;  // 313
    const int AGG_GRID  = (N_NODES + 3) / 4;    // 5000

    for (int l = 0; l < 4; ++l) {
        agg_kernel<<<AGG_GRID, 256, 0, stream>>>(X2, row_off, ssrc, inv_deg, X2 + 256);
        // in-place: reads X2[:, 0:512], writes X2[:, 0:256]
        gemm_ln_relu<16, 512, bf16><<<GEMM_GRID, 256, 0, stream>>>(
            X2, LDX, WTc + (size_t)l * 256 * 512,
            bconv + (size_t)l * 256, conv_gamma + (size_t)l * 256, conv_beta + (size_t)l * 256,
            X2, LDX, N_NODES);
    }
    // head: h1 -> X2[:, 256:512], then final fp32 -> d_out
    gemm_ln_relu<16, 256, bf16><<<GEMM_GRID, 256, 0, stream>>>(
        X2, LDX, W1T, (const float*)nullptr, g1, b1, X2 + 256, LDX, N_NODES);
    gemm_ln_relu<8, 256, float><<<GEMM_GRID, 256, 0, stream>>>(
        X2 + 256, LDX, W2T, (const float*)nullptr, g2, b2, out, 128, N_NODES);
    (void)ws_size; (void)n_in; (void)in_sizes; (void)out_size;
}